// Round 1
// 176.628 us; speedup vs baseline: 1.0522x; 1.0522x over previous
//
#include <hip/hip_runtime.h>

#define NW 2048
#define NS 8192
#define NSL 128            // bins of 16 rows; slice = 16*2048 u16 = 64 KB LDS

typedef int            i32x4 __attribute__((ext_vector_type(4)));
typedef unsigned int   u32x4 __attribute__((ext_vector_type(4)));
typedef float          f32x4 __attribute__((ext_vector_type(4)));
typedef unsigned short u16x4 __attribute__((ext_vector_type(4)));

// ============================ PRIMARY PATH =================================
// P1+P2 fused: 8-bit table pack + per-sample counting-sort of pair keys by bin.
// All stores are CACHEABLE (no nontemporal) — downstream kernels consume them,
// and the full working set (~150 MB) fits the 256 MB L3.
__global__ __launch_bounds__(256) void bucket4_kernel(
    const i32x4* __restrict__ samples4,
    const f32x4* __restrict__ bigram4, const f32x4* __restrict__ bias4,
    u16x4* __restrict__ tab4,
    unsigned short* __restrict__ gkeys,
    unsigned* __restrict__ oc_q,               // [q][s] slice-major, (cnt<<16)|off
    int* __restrict__ fl,
    unsigned long long* __restrict__ acc)
{
    __shared__ unsigned short srow[4][NW];
    __shared__ unsigned short kbuf[4][NW];
    __shared__ unsigned hist[4][NSL];
    __shared__ unsigned cur[4][NSL];
    const int t = threadIdx.x, w = t >> 6, l = t & 63;
    const int s = blockIdx.x * 4 + w;

    // fused table pack: cell = (round(bias*255)<<8) | round(bigram*255)
    // grid (2048 blocks x 256 thr) covers NW*NW/4 u16x4 cells in exactly 2 reps
    {
        int i0 = blockIdx.x * 256 + t;
#pragma unroll
        for (int rep = 0; rep < 2; ++rep) {
            int i = i0 + rep * (2048 * 256);
            f32x4 gg = bigram4[i];
            f32x4 bb = bias4[i];
            u16x4 o;
            o.x = (unsigned short)((__float2uint_rn(bb.x * 255.f) << 8) | __float2uint_rn(gg.x * 255.f));
            o.y = (unsigned short)((__float2uint_rn(bb.y * 255.f) << 8) | __float2uint_rn(gg.y * 255.f));
            o.z = (unsigned short)((__float2uint_rn(bb.z * 255.f) << 8) | __float2uint_rn(gg.z * 255.f));
            o.w = (unsigned short)((__float2uint_rn(bb.w * 255.f) << 8) | __float2uint_rn(gg.w * 255.f));
            tab4[i] = o;
        }
    }
    // fused acc zero (replaces hipMemsetAsync): 2048 blocks x 4 = NS entries
    if (t < 4) acc[blockIdx.x * 4 + t] = 0ull;

    const i32x4* rp = samples4 + (size_t)s * (NW / 4);
#pragma unroll
    for (int k = 0; k < 8; ++k) {
        i32x4 v = rp[l + 64 * k];
        u16x4 o;
        o.x = (unsigned short)v.x; o.y = (unsigned short)v.y;
        o.z = (unsigned short)v.z; o.w = (unsigned short)v.w;
        ((u16x4*)srow[w])[l + 64 * k] = o;
    }
    hist[w][l] = 0; hist[w][l + 64] = 0;
    __syncthreads();

#pragma unroll
    for (int k = 0; k < 32; ++k) {
        int j = l + 64 * k;
        if (j < NW - 1) atomicAdd(&hist[w][srow[w][j] >> 4], 1u);
    }
    __syncthreads();

    unsigned c0 = hist[w][l], c1 = hist[w][l + 64];
    unsigned x0 = c0, x1 = c1;
#pragma unroll
    for (int d = 1; d < 64; d <<= 1) {
        unsigned y0 = __shfl_up(x0, d);
        unsigned y1 = __shfl_up(x1, d);
        if (l >= d) { x0 += y0; x1 += y1; }
    }
    unsigned tot0 = __shfl(x0, 63);
    unsigned off0 = x0 - c0;
    unsigned off1 = tot0 + x1 - c1;
    cur[w][l] = off0; cur[w][l + 64] = off1;
    __syncthreads();

#pragma unroll
    for (int k = 0; k < 32; ++k) {
        int j = l + 64 * k;
        if (j < NW - 1) {
            unsigned r = srow[w][j], c = srow[w][j + 1];
            unsigned pos = atomicAdd(&cur[w][r >> 4], 1u);
            // key stored PRE-SHIFTED (x2) = LDS byte address into the 64 KB slice
            kbuf[w][pos] = (unsigned short)(((((r & 15u) << 11) | c) << 1));
        }
    }
    __syncthreads();

#pragma unroll
    for (int k = 0; k < 4; ++k)
        ((u32x4*)(gkeys + (size_t)s * NW))[l + 64 * k] = ((u32x4*)kbuf[w])[l + 64 * k];
    // direct transposed oc write (kills the transpose kernel + oc_s buffer):
    // 2 scattered dword stores per lane, absorbed by L2 (oc_q is 4 MB)
    oc_q[(size_t)l * NS + s]        = (c0 << 16) | off0;
    oc_q[(size_t)(l + 64) * NS + s] = (c1 << 16) | off1;
    if (l == 0) { fl[2 * s] = (int)srow[w][0]; fl[2 * s + 1] = (int)srow[w][NW - 1]; }
}

// P3: lane-per-sample LDS-table gather.
//  - each lane owns ONE sample's contiguous key segment for this bin:
//    no oc broadcast, no cross-lane reduce, one atomic per lane at the end;
//  - batches of 8 independent key loads + 8 independent ds_read_u16 so
//    latencies overlap; wave-uniform trip count (wave-max of cnt);
//  - pad slots are forced to key 0 (-> stab byte 0) and subtracted exactly
//    afterwards: integer math, result bit-identical to the old reduction.
__global__ __launch_bounds__(1024) void gather7_kernel(
    const unsigned short* __restrict__ tab,
    const unsigned short* __restrict__ gkeys,
    const unsigned* __restrict__ oc_q,
    unsigned long long* __restrict__ acc)
{
    __shared__ unsigned short stab[16 * NW];      // 64 KB slice
    const int q = blockIdx.x;
    const int bin = ((q & 7) << 4) | (q >> 3);    // XCD-contiguous bin mapping
    const int t = threadIdx.x;

    const u32x4* srcp = (const u32x4*)(tab + (size_t)bin * 16 * NW);
    u32x4* dstp = (u32x4*)stab;
#pragma unroll
    for (int k = 0; k < 4; ++k)
        dstp[t + 1024 * k] = srcp[t + 1024 * k];

    const int sid = blockIdx.y * 1024 + t;        // one sample per lane
    unsigned oc = oc_q[(size_t)bin * NS + sid];
    __syncthreads();

    const unsigned off = oc & 0xffffu;
    const unsigned cnt = oc >> 16;
    const unsigned short* kp = gkeys + (size_t)sid * NW + off;
    const unsigned v0 = (unsigned)stab[0];        // pad-slot value

    // wave-uniform trip count = max(cnt) over the wave
    unsigned cm = cnt;
#pragma unroll
    for (int d = 32; d; d >>= 1) {
        unsigned o = __shfl_xor(cm, d);
        cm = (o > cm) ? o : cm;
    }

    unsigned T = 0, G = 0;                        // T = sum(v), G = sum(v & 0xff)
    for (unsigned p = 0; p < cm; p += 8) {
        unsigned short kr[8];
#pragma unroll
        for (int i = 0; i < 8; ++i)               // 8 independent loads, imm offsets
            kr[i] = kp[p + i];                    // may over-read; masked below
        int rem = (int)(cnt - p);                 // negative once lane is done
#pragma unroll
        for (int i = 0; i < 8; ++i) {
            unsigned k2 = (i < rem) ? (unsigned)kr[i] : 0u;   // byte addr (pre-shifted)
            unsigned v = (unsigned)*(const unsigned short*)((const char*)stab + k2);
            T += v;
            G += v & 0xffu;
        }
    }
    // exact correction for the pad slots (each added stab[0])
    unsigned slots = (cm + 7u) & ~7u;
    unsigned extra = slots - cnt;
    T -= extra * v0;
    G -= extra * (v0 & 0xffu);
    unsigned B = (T - G) >> 8;                    // sum of high bytes, exact

    atomicAdd(&acc[sid], ((unsigned long long)B << 32) | (unsigned long long)G);
}

// P4a: parallel finalize partials — 32 blocks x 256 thr, one sample/thread.
__global__ __launch_bounds__(256) void finalize_part_kernel(
    const float* __restrict__ bigram, const float* __restrict__ bias,
    const float* __restrict__ start, const float* __restrict__ endv,
    const unsigned long long* __restrict__ acc, const int* __restrict__ fl,
    double* __restrict__ part)
{
    const int b = blockIdx.x, t = threadIdx.x;
    const int s = b * 256 + t;
    unsigned long long a = acc[s];
    double u = (double)(unsigned)(a & 0xffffffffu) * (1.0 / 255.0)
             + (double)start[fl[2 * s]] + (double)endv[fl[2 * s + 1]];
    double bb = (double)(unsigned)(a >> 32) * (1.0 / 255.0);
    double su = u, sw = u * (u + bb), diag = 0.0;
    if (s < NW - 1) {
        size_t idx = (size_t)s * NW + (size_t)s + 1;
        diag = (double)bigram[idx] + (double)bias[idx];
    }
#pragma unroll
    for (int o = 32; o; o >>= 1) {
        su   += __shfl_down(su, o);
        sw   += __shfl_down(sw, o);
        diag += __shfl_down(diag, o);
    }
    __shared__ double sh[3][4];
    if ((t & 63) == 0) { int w = t >> 6; sh[0][w] = su; sh[1][w] = sw; sh[2][w] = diag; }
    __syncthreads();
    if (t == 0) {
        su   = sh[0][0] + sh[0][1] + sh[0][2] + sh[0][3];
        sw   = sh[1][0] + sh[1][1] + sh[1][2] + sh[1][3];
        diag = sh[2][0] + sh[2][1] + sh[2][2] + sh[2][3];
        part[3 * b] = su; part[3 * b + 1] = sw; part[3 * b + 2] = diag;
    }
}

// P4b: combine 32 partial triples.
__global__ __launch_bounds__(64) void finalize_final_kernel(
    const float* __restrict__ start, const float* __restrict__ endv,
    const double* __restrict__ part, float* __restrict__ out)
{
    if (threadIdx.x == 0) {
        double su = 0.0, sw = 0.0, diag = 0.0;
        for (int b = 0; b < 32; ++b) {
            su += part[3 * b]; sw += part[3 * b + 1]; diag += part[3 * b + 2];
        }
        double C = (double)start[0] + (double)endv[NW - 1] + diag;
        out[0] = (float)(sw / su - C);
    }
}

// ====================== FALLBACK (round-1 structure) ========================
__global__ __launch_bounds__(256) void interleave_kernel(
    const float* __restrict__ bigram, const float* __restrict__ bias,
    float2* __restrict__ comb)
{
    size_t total = (size_t)NW * NW;
    size_t stride = (size_t)gridDim.x * blockDim.x;
    for (size_t i = (size_t)blockIdx.x * blockDim.x + threadIdx.x; i < total; i += stride)
        comb[i] = make_float2(bigram[i], bias[i]);
}

template <bool USE_COMB>
__global__ __launch_bounds__(256) void sample_kernel(
    const float2* __restrict__ comb,
    const float* __restrict__ bigram, const float* __restrict__ bias,
    const float* __restrict__ start, const float* __restrict__ endv,
    const int* __restrict__ samples,
    float* __restrict__ u_out, float* __restrict__ b_out)
{
    __shared__ int srow[NW];
    __shared__ float su[4], sb[4];
    const int i = blockIdx.x;
    const int t = threadIdx.x;
    const int4* row4 = (const int4*)(samples + (size_t)i * NW);
    int4* srow4 = (int4*)srow;
    srow4[t]       = row4[t];
    srow4[t + 256] = row4[t + 256];
    __syncthreads();
    float u = 0.f, b = 0.f;
#pragma unroll
    for (int k = 0; k < 8; ++k) {
        int j = t + k * 256;
        if (j < NW - 1) {
            int r = srow[j], c = srow[j + 1];
            size_t idx = ((size_t)r << 11) + (size_t)c;
            if (USE_COMB) { float2 v = comb[idx]; u += v.x; b += v.y; }
            else          { u += bigram[idx]; b += bias[idx]; }
        }
    }
#pragma unroll
    for (int off = 32; off; off >>= 1) {
        u += __shfl_down(u, off);
        b += __shfl_down(b, off);
    }
    if ((t & 63) == 0) { su[t >> 6] = u; sb[t >> 6] = b; }
    __syncthreads();
    if (t == 0) {
        u = su[0] + su[1] + su[2] + su[3];
        b = sb[0] + sb[1] + sb[2] + sb[3];
        u += start[srow[0]] + endv[srow[NW - 1]];
        u_out[i] = u;
        b_out[i] = b;
    }
}

__global__ __launch_bounds__(1024) void finalize_kernel(
    const float* __restrict__ bigram, const float* __restrict__ bias,
    const float* __restrict__ start, const float* __restrict__ endv,
    const float* __restrict__ u_in, const float* __restrict__ b_in,
    float* __restrict__ out)
{
    const int t = threadIdx.x;
    double su = 0.0, sw = 0.0, diag = 0.0;
    for (int i = t; i < NS; i += 1024) {
        double u = (double)u_in[i];
        su += u;
        sw += u * (u + (double)b_in[i]);
    }
    for (int k = t; k < NW - 1; k += 1024) {
        size_t idx = (size_t)k * NW + (size_t)k + 1;
        diag += (double)bigram[idx] + (double)bias[idx];
    }
#pragma unroll
    for (int off = 32; off; off >>= 1) {
        su   += __shfl_down(su, off);
        sw   += __shfl_down(sw, off);
        diag += __shfl_down(diag, off);
    }
    __shared__ double s1[16], s2[16], s3[16];
    if ((t & 63) == 0) { int w = t >> 6; s1[w] = su; s2[w] = sw; s3[w] = diag; }
    __syncthreads();
    if (t == 0) {
        for (int w = 1; w < 16; ++w) { su += s1[w]; sw += s2[w]; diag += s3[w]; }
        double C = (double)start[0] + (double)endv[NW - 1] + diag;
        out[0] = (float)(sw / su - C);
    }
}

// ===========================================================================
extern "C" void kernel_launch(void* const* d_in, const int* in_sizes, int n_in,
                              void* d_out, int out_size, void* d_ws, size_t ws_size,
                              hipStream_t stream) {
    const float* bigram  = (const float*)d_in[0];
    const float* start   = (const float*)d_in[1];
    const float* endv    = (const float*)d_in[2];
    const float* bias    = (const float*)d_in[3];
    const int*   samples = (const int*)d_in[4];
    float* out = (float*)d_out;

    // primary ws layout (note: gather over-reads gkeys by <8 KB -> oc_q pads it)
    size_t off = 0;
    size_t tab_off  = off; off += (size_t)NW * NW * 2;    // 8 MB u16 table
    off = (off + 255) & ~(size_t)255;
    size_t keys_off = off; off += (size_t)NS * NW * 2;    // 32 MB u16 keys
    off = (off + 255) & ~(size_t)255;
    size_t ocq_off  = off; off += (size_t)NS * NSL * 4;   // 4 MB oc slice-major
    off = (off + 255) & ~(size_t)255;
    size_t fl_off   = off; off += (size_t)NS * 2 * 4;     // 64 KB first/last
    off = (off + 255) & ~(size_t)255;
    size_t acc_off  = off; off += (size_t)NS * 8;         // 64 KB packed acc
    off = (off + 255) & ~(size_t)255;
    size_t part_off = off; off += (size_t)32 * 3 * 8;     // 768 B fp64 partials
    size_t need_primary = off;

    if (ws_size >= need_primary) {
        unsigned short*     tab   = (unsigned short*)((char*)d_ws + tab_off);
        unsigned short*     gkeys = (unsigned short*)((char*)d_ws + keys_off);
        unsigned*           oc_q  = (unsigned*)((char*)d_ws + ocq_off);
        int*                fl    = (int*)((char*)d_ws + fl_off);
        unsigned long long* acc   = (unsigned long long*)((char*)d_ws + acc_off);
        double*             part  = (double*)((char*)d_ws + part_off);

        bucket4_kernel<<<NS / 4, 256, 0, stream>>>(
            (const i32x4*)samples, (const f32x4*)bigram, (const f32x4*)bias,
            (u16x4*)tab, gkeys, oc_q, fl, acc);
        gather7_kernel<<<dim3(NSL, NS / 1024), 1024, 0, stream>>>(
            tab, gkeys, oc_q, acc);
        finalize_part_kernel<<<32, 256, 0, stream>>>(
            bigram, bias, start, endv, acc, fl, part);
        finalize_final_kernel<<<1, 64, 0, stream>>>(start, endv, part, out);
        return;
    }

    // fallback: round-1 structure
    float* u_out = (float*)d_ws;
    float* b_out = u_out + NS;
    size_t comb_off = ((size_t)NS * 2 * sizeof(float) + 255) & ~(size_t)255;
    size_t comb_bytes = (size_t)NW * NW * sizeof(float2);
    bool use_comb = (ws_size >= comb_off + comb_bytes);
    if (use_comb) {
        float2* comb = (float2*)((char*)d_ws + comb_off);
        interleave_kernel<<<4096, 256, 0, stream>>>(bigram, bias, comb);
        sample_kernel<true><<<NS, 256, 0, stream>>>(comb, bigram, bias, start, endv,
                                                    samples, u_out, b_out);
    } else {
        sample_kernel<false><<<NS, 256, 0, stream>>>(nullptr, bigram, bias, start, endv,
                                                     samples, u_out, b_out);
    }
    finalize_kernel<<<1, 1024, 0, stream>>>(bigram, bias, start, endv, u_out, b_out, out);
}